// Round 1
// baseline (196.362 us; speedup 1.0000x reference)
//
#include <hip/hip_runtime.h>

#define NBINS 256

// ---- order-preserving float<->uint encoding for atomic min/max ----
__device__ __forceinline__ unsigned int f2o(float f) {
    unsigned int u = __float_as_uint(f);
    return (u & 0x80000000u) ? ~u : (u | 0x80000000u);
}
__device__ __forceinline__ float o2f(unsigned int u) {
    unsigned int v = (u & 0x80000000u) ? (u & 0x7fffffffu) : ~u;
    return __uint_as_float(v);
}

// ws layout (uint32): ws[0]=ordered min, ws[1]=ordered max, ws[2..257]=hist bins
__global__ void hrt_init(unsigned int* ws) {
    int i = threadIdx.x;
    if (i == 0) ws[0] = 0xFFFFFFFFu;
    if (i == 1) ws[1] = 0u;
    ws[2 + i] = 0u;  // blockDim.x == NBINS
}

__global__ void hrt_minmax(const float4* __restrict__ in, int n4, unsigned int* ws) {
    float mn = INFINITY, mx = -INFINITY;
    int stride = gridDim.x * blockDim.x;
    for (int i = blockIdx.x * blockDim.x + threadIdx.x; i < n4; i += stride) {
        float4 v = in[i];
        mn = fminf(mn, fminf(fminf(v.x, v.y), fminf(v.z, v.w)));
        mx = fmaxf(mx, fmaxf(fmaxf(v.x, v.y), fmaxf(v.z, v.w)));
    }
    #pragma unroll
    for (int off = 32; off > 0; off >>= 1) {
        mn = fminf(mn, __shfl_down(mn, off));
        mx = fmaxf(mx, __shfl_down(mx, off));
    }
    __shared__ float smn[4], smx[4];
    int lane = threadIdx.x & 63, wid = threadIdx.x >> 6;
    if (lane == 0) { smn[wid] = mn; smx[wid] = mx; }
    __syncthreads();
    if (threadIdx.x == 0) {
        #pragma unroll
        for (int w = 1; w < 4; ++w) { mn = fminf(mn, smn[w]); mx = fmaxf(mx, smx[w]); }
        atomicMin(&ws[0], f2o(mn));
        atomicMax(&ws[1], f2o(mx));
    }
}

__global__ void hrt_hist(const float4* __restrict__ in, int n4,
                         const unsigned int* __restrict__ ws) {
    __shared__ unsigned int h[4][NBINS];  // per-wave privatized histograms
    for (int i = threadIdx.x; i < 4 * NBINS; i += blockDim.x)
        ((unsigned int*)h)[i] = 0u;
    __syncthreads();
    float mn = o2f(ws[0]);
    float mx = o2f(ws[1]);
    float scale = (float)NBINS / (mx - mn);
    int wid = threadIdx.x >> 6;
    int stride = gridDim.x * blockDim.x;
    for (int i = blockIdx.x * blockDim.x + threadIdx.x; i < n4; i += stride) {
        float4 v = in[i];
        int b0 = (int)((v.x - mn) * scale); b0 = b0 > NBINS - 1 ? NBINS - 1 : b0;
        int b1 = (int)((v.y - mn) * scale); b1 = b1 > NBINS - 1 ? NBINS - 1 : b1;
        int b2 = (int)((v.z - mn) * scale); b2 = b2 > NBINS - 1 ? NBINS - 1 : b2;
        int b3 = (int)((v.w - mn) * scale); b3 = b3 > NBINS - 1 ? NBINS - 1 : b3;
        atomicAdd(&h[wid][b0], 1u);
        atomicAdd(&h[wid][b1], 1u);
        atomicAdd(&h[wid][b2], 1u);
        atomicAdd(&h[wid][b3], 1u);
    }
    __syncthreads();
    unsigned int* gh = (unsigned int*)ws + 2;
    for (int i = threadIdx.x; i < NBINS; i += blockDim.x) {
        unsigned int s = h[0][i] + h[1][i] + h[2][i] + h[3][i];
        if (s) atomicAdd(&gh[i], s);
    }
}

__global__ void hrt_finalize(const unsigned int* __restrict__ ws, float* __restrict__ out) {
    if (threadIdx.x != 0 || blockIdx.x != 0) return;
    const unsigned int* h = ws + 2;
    unsigned long long total = 0;
    for (int i = 0; i < NBINS; ++i) total += h[i];
    double thr_lo = (double)total * ((1.0 - 0.99) / 2.0);
    double thr_hi = (double)total * ((1.0 + 0.99) / 2.0);
    unsigned long long cum = 0;
    int lo = 0, hi = 0;
    bool flo = false, fhi = false;
    for (int i = 0; i < NBINS; ++i) {
        cum += h[i];
        double c = (double)cum;
        if (!flo && c > thr_lo) { lo = i; flo = true; }
        if (!fhi && c > thr_hi) { hi = i; fhi = true; }
    }
    float mn = o2f(ws[0]), mx = o2f(ws[1]);
    // np.linspace computes in f64 then casts to f32
    double delta = ((double)mx - (double)mn) / (double)NBINS;
    out[0] = (float)((double)mn + (double)lo * delta);
    out[1] = (float)((double)mn + (double)hi * delta);
}

extern "C" void kernel_launch(void* const* d_in, const int* in_sizes, int n_in,
                              void* d_out, int out_size, void* d_ws, size_t ws_size,
                              hipStream_t stream) {
    const float4* in = (const float4*)d_in[0];
    int n = in_sizes[0];
    int n4 = n / 4;
    unsigned int* ws = (unsigned int*)d_ws;
    float* out = (float*)d_out;

    hrt_init<<<1, NBINS, 0, stream>>>(ws);
    hrt_minmax<<<2048, 256, 0, stream>>>(in, n4, ws);
    hrt_hist<<<2048, 256, 0, stream>>>(in, n4, ws);
    hrt_finalize<<<1, 64, 0, stream>>>(ws, out);
}